// Round 2
// baseline (312.069 us; speedup 1.0000x reference)
//
#include <hip/hip_runtime.h>
#include <stdint.h>

// B=8, S=4096, H=16, E=64, s=64, conv kernel len 127 (fwd FFT len) / 126 (inv FFT len).
#define OUT2_OFF 33554432ull

// ---------------------------------------------------------------------------
// Kernel 1: build G[h][t][j] (16 x 64 x 64 f32) implementing
//   y = irfft_126( rfft_127(pad63(a)) * rfft_127(z_h) )[0:64]  ==  G_h @ a
// Grid 256 = (h, tq); 256 threads. Each block: Z_h spectrum (64 bins) in LDS,
// then 256 G entries (t in [4tq,4tq+4), all j), 62-term k-loop with sincosf.
// ---------------------------------------------------------------------------
__global__ __launch_bounds__(256) void prep_g_kernel(
        const float* __restrict__ wgt,   // [16][127] f32
        float* __restrict__ G) {         // [16][64][64] f32
    const int h  = blockIdx.x >> 4;
    const int tq = blockIdx.x & 15;
    const int tid = threadIdx.x;
    __shared__ float zl[127];
    __shared__ float ZA[64], ZB[64];

    if (tid < 127) zl[tid] = wgt[h * 127 + tid];
    __syncthreads();
    if (tid < 64) {
        const float w127 = 6.28318530717958647692f / 127.0f;
        float a = 0.f, b = 0.f;
        for (int m = 0; m < 127; ++m) {
            const int r = (tid * m) % 127;
            float sv, cv; sincosf((float)r * w127, &sv, &cv);
            a += zl[m] * cv;   // Re(Z_k)
            b -= zl[m] * sv;   // Im(Z_k)  (forward: e^{-i...})
        }
        ZA[tid] = a; ZB[tid] = b;
    }
    __syncthreads();

    const int t = tq * 4 + (tid >> 6);
    const int j = tid & 63;
    const int jj = 63 + j;                 // position of a[j] in the padded signal
    const float w126 = 6.28318530717958647692f / 126.0f;
    const float w127 = 6.28318530717958647692f / 127.0f;

    float acc = ZA[0];                     // k = 0 term
    for (int k = 1; k <= 62; ++k) {
        const int rb = (k * t) % 126;      // inverse basis e^{+i 2pi k t /126}
        const int ra = (k * jj) % 127;     // forward      e^{-i 2pi k jj/127}
        const float ph = (float)rb * w126 - (float)ra * w127;
        float sv, cv; sincosf(ph, &sv, &cv);
        acc += 2.f * (ZA[k] * cv - ZB[k] * sv);
    }
    {   // Nyquist bin of the length-126 inverse: (-1)^t * Re(Z63 * e^{-i a})
        const int ra = (63 * jj) % 127;
        float sv, cv; sincosf((float)ra * w127, &sv, &cv);
        const float term = ZA[63] * cv + ZB[63] * sv;
        acc += (t & 1) ? -term : term;
    }
    G[((size_t)h * 64 + t) * 64 + j] = acc * (1.0f / 126.0f);
}

// ---------------------------------------------------------------------------
// Kernel 2: v (f32 [b][t][h][e]) -> us[bh][i][e] (row sums over j, complete) and
// vs_part[ig][bh][j][e] (col sums over the block's 16 i's).
// Grid 512 = (bh, ig); 256 threads. Rows are 256 B contiguous; one wave issues
// 4 rows x 256 B per step. Next-iteration loads issued before the butterfly.
// ---------------------------------------------------------------------------
__global__ __launch_bounds__(256) void reduce_kernel(
        const float* __restrict__ v,
        float* __restrict__ us,         // [128][64][64]
        float* __restrict__ vs_part) {  // [4][128][64][64]
    const int bid = blockIdx.x;
    const int ig = bid & 3, bh = bid >> 2;
    const int b = bh >> 4, h = bh & 15;
    const int tid = threadIdx.x;
    const int q  = tid & 15;            // float4 e-chunk (e = 4q..4q+3)
    const int rs = tid >> 4;            // 0..15 j-sub
    const int w = tid >> 6, lane = tid & 63;

    __shared__ float us_red[4][16][4];

    const float4* v4 = (const float4*)v;
    const size_t base4 = (size_t)b * 4096 * 256 + (size_t)h * 16 + q;

    float vsacc[4][4];
#pragma unroll
    for (int a = 0; a < 4; ++a)
#pragma unroll
        for (int c = 0; c < 4; ++c) vsacc[a][c] = 0.f;

    float4 cur[4], nxt[4];
#pragma unroll
    for (int jh = 0; jh < 4; ++jh) {
        const int t = (ig * 16) * 64 + jh * 16 + rs;
        cur[jh] = v4[base4 + (size_t)t * 256];
    }

    for (int il = 0; il < 16; ++il) {
        const int i = ig * 16 + il;
        if (il < 15) {
#pragma unroll
            for (int jh = 0; jh < 4; ++jh) {
                const int t = (i + 1) * 64 + jh * 16 + rs;
                nxt[jh] = v4[base4 + (size_t)t * 256];
            }
        }
        float p[4] = {0.f, 0.f, 0.f, 0.f};
#pragma unroll
        for (int jh = 0; jh < 4; ++jh) {
            p[0] += cur[jh].x; p[1] += cur[jh].y; p[2] += cur[jh].z; p[3] += cur[jh].w;
            vsacc[jh][0] += cur[jh].x; vsacc[jh][1] += cur[jh].y;
            vsacc[jh][2] += cur[jh].z; vsacc[jh][3] += cur[jh].w;
        }
        // sum over the wave's 4 j-sub groups (lane bits 4,5)
#pragma unroll
        for (int mask = 16; mask <= 32; mask <<= 1)
#pragma unroll
            for (int c = 0; c < 4; ++c) p[c] += __shfl_xor(p[c], mask);
        if (lane < 16) {
#pragma unroll
            for (int c = 0; c < 4; ++c) us_red[w][lane][c] = p[c];
        }
        __syncthreads();
        if (tid < 64) {
            const int q2 = tid >> 2, c2 = tid & 3;
            const float ssum = us_red[0][q2][c2] + us_red[1][q2][c2]
                             + us_red[2][q2][c2] + us_red[3][q2][c2];
            us[((size_t)bh * 64 + i) * 64 + tid] = ssum;
        }
        __syncthreads();
#pragma unroll
        for (int jh = 0; jh < 4; ++jh) cur[jh] = nxt[jh];
    }
#pragma unroll
    for (int jh = 0; jh < 4; ++jh) {
        const int j = jh * 16 + rs;
        *(float4*)(vs_part + (((size_t)ig * 128 + bh) * 64 + j) * 64 + q * 4) =
            make_float4(vsacc[jh][0], vsacc[jh][1], vsacc[jh][2], vsacc[jh][3]);
    }
}

// ---------------------------------------------------------------------------
// Kernel 3: fused conv + emit.
// bid < 512: block (bh, tq): rxv[t][e] = sum_j G[t][j] vs[j][e] (all 64 t),
//            rxu[i][e] for i in [16tq,16tq+16), all in LDS; then stream
//            out1[b, t, h, e] = rxv[t&63][e] + rxu[t>>6][e] for its 1024 t's
//            (one 64-float row per wave per step, coalesced 256 B stores).
// bid >= 512: 64 tail blocks emit out2 from G and o_.
// ---------------------------------------------------------------------------
__global__ __launch_bounds__(256) void convemit_kernel(
        const float* __restrict__ G,
        const float* __restrict__ us,
        const float* __restrict__ vs_part,
        const float* __restrict__ ovec,
        float* __restrict__ out) {
    const int bid = blockIdx.x;
    const int tid = threadIdx.x;
    if (bid < 512) {
        const int bh = bid >> 2, tq = bid & 3;
        const int b = bh >> 4, h = bh & 15;
        __shared__ float Gl[64 * 65];       // padded stride 65
        __shared__ float usl[64 * 64];
        __shared__ float vsl[64 * 64];
        __shared__ float rxv_l[64 * 68];    // padded stride 68
        __shared__ float rxu_l[16 * 68];

        for (int k = 0; k < 16; ++k) {
            const int idx = k * 256 + tid;
            usl[idx] = us[(size_t)bh * 4096 + idx];
            float a = 0.f;
#pragma unroll
            for (int ig = 0; ig < 4; ++ig)
                a += vs_part[((size_t)ig * 128 + bh) * 4096 + idx];
            vsl[idx] = a;
            Gl[(idx >> 6) * 65 + (idx & 63)] = G[(size_t)h * 4096 + idx];
        }
        __syncthreads();

        const int q = tid & 15;             // float4 e-chunk
        const int tb = tid >> 4;            // 0..15
        const float4* us4 = (const float4*)usl;
        const float4* vs4 = (const float4*)vsl;

        for (int r = 0; r < 4; ++r) {       // rxv rows: t = 4*tb + r
            const int t = tb * 4 + r;
            float4 acc = {0.f, 0.f, 0.f, 0.f};
            for (int j = 0; j < 64; ++j) {
                const float g = Gl[t * 65 + j];
                const float4 vv = vs4[j * 16 + q];
                acc.x += g * vv.x; acc.y += g * vv.y;
                acc.z += g * vv.z; acc.w += g * vv.w;
            }
            float* d = rxv_l + t * 68 + q * 4;
            d[0] = acc.x; d[1] = acc.y; d[2] = acc.z; d[3] = acc.w;
        }
        {                                   // rxu row: i = 16*tq + tb
            const int i = tq * 16 + tb;
            float4 acc = {0.f, 0.f, 0.f, 0.f};
            for (int k2 = 0; k2 < 64; ++k2) {
                const float g = Gl[i * 65 + k2];
                const float4 uu = us4[k2 * 16 + q];
                acc.x += g * uu.x; acc.y += g * uu.y;
                acc.z += g * uu.z; acc.w += g * uu.w;
            }
            float* d = rxu_l + tb * 68 + q * 4;
            d[0] = acc.x; d[1] = acc.y; d[2] = acc.z; d[3] = acc.w;
        }
        __syncthreads();

        // store phase: one t-row (64 floats, 256 B) per wave per step;
        // LDS reads are lane-consecutive (2-way bank aliasing = free).
        const int w = tid >> 6, lane = tid & 63;
        for (int it = 0; it < 256; ++it) {
            const int t_loc = it * 4 + w;
            const int t = tq * 1024 + t_loc;
            const int j = t_loc & 63;
            const int il = t_loc >> 6;
            const float val = rxv_l[j * 68 + lane] + rxu_l[il * 68 + lane];
            out[(((size_t)(b * 4096 + t)) * 16 + h) * 64 + lane] = val;
        }
    } else {
        const int bz = bid - 512;           // 0..63 : t>>6 block for out2
        __shared__ float ol[64];
        __shared__ float zpb[1024];         // [h][n]
        if (tid < 64) ol[tid] = ovec[tid];
        __syncthreads();
#pragma unroll
        for (int r = 0; r < 4; ++r) {
            const int idx = tid + 256 * r;
            const int h = idx >> 6, n = idx & 63;
            float acc = 0.f;
            for (int j = 0; j < 64; ++j)
                acc += ol[j] * G[(size_t)h * 4096 + n * 64 + j];
            zpb[idx] = acc * 64.f;          // * s
        }
        __syncthreads();
#pragma unroll
        for (int r = 0; r < 4; ++r) {
            const int k = tid + 256 * r;
            const int hh = k & 15, c = k >> 4;
            out[OUT2_OFF + ((size_t)(bz * 64 + c)) * 16 + hh] =
                zpb[hh * 64 + c] + zpb[hh * 64 + bz];
        }
    }
}

extern "C" void kernel_launch(void* const* d_in, const int* in_sizes, int n_in,
                              void* d_out, int out_size, void* d_ws, size_t ws_size,
                              hipStream_t stream) {
    const float* v    = (const float*)d_in[0];   // (8,4096,16,64) f32
    const float* wgt  = (const float*)d_in[1];   // (1,16,127) f32
    const float* ovec = (const float*)d_in[2];   // (64,) f32

    float* G       = (float*)d_ws;               // 65536 floats   (256 KiB)
    float* us      = G + 65536;                  // 524288 floats  (2 MiB)
    float* vs_part = us + 524288;                // 2097152 floats (8 MiB)
    float* out     = (float*)d_out;

    hipLaunchKernelGGL(prep_g_kernel,   dim3(256),     dim3(256), 0, stream, wgt, G);
    hipLaunchKernelGGL(reduce_kernel,   dim3(512),     dim3(256), 0, stream, v, us, vs_part);
    hipLaunchKernelGGL(convemit_kernel, dim3(512 + 64), dim3(256), 0, stream,
                       G, us, vs_part, ovec, out);
}

// Round 4
// 251.966 us; speedup vs baseline: 1.2385x; 1.2385x over previous
//
#include <hip/hip_runtime.h>
#include <stdint.h>

// B=8, S=4096, H=16, E=64, s=64; rfft len 127, irfft len 126.
#define OUT2_OFF 33554432ull

typedef float v4f __attribute__((ext_vector_type(4)));

// ---------------------------------------------------------------------------
// Kernel 1 (fused dispatch):
//  bid < 512 : reduce path. Block (bh, ig): 16 i-rows. Barrier-free:
//    lane bits 0-3 = j-sub (rs), q = 4w + (lane>>4) = e-chunk. Row sums via
//    in-thread jh accumulate + shfl_xor butterfly over masks 1,2,4,8.
//    Column sums accumulate in 4 v4f registers, stored once at the end.
//  bid >= 512: prep path (256 blocks): build G[h][t][j] via twiddle tables.
// ---------------------------------------------------------------------------
__global__ __launch_bounds__(256) void fused1_kernel(
        const float* __restrict__ v,      // [8][4096][16][64]
        const float* __restrict__ wgt,    // [16][127]
        float* __restrict__ us,           // [128][64][64]
        float* __restrict__ vs_part,      // [4][128][64][64]
        float* __restrict__ G) {          // [16][64][64]
    const int bid = blockIdx.x;
    const int tid = threadIdx.x;

    if (bid < 512) {
        const int ig = bid & 3, bh = bid >> 2;
        const int b = bh >> 4, h = bh & 15;
        const int w = tid >> 6, lane = tid & 63;
        const int rs = lane & 15;            // j-sub within wave
        const int q  = 4 * w + (lane >> 4);  // e-chunk (float4)

        const v4f* v4 = (const v4f*)v;
        const size_t base4 = (size_t)b * 1048576 + (size_t)h * 16 + q;

        v4f vsacc[4];
#pragma unroll
        for (int a = 0; a < 4; ++a) vsacc[a] = (v4f)0.f;
        v4f cur[4], nxt[4];

        {
            const int t0 = (ig * 16) * 64;
#pragma unroll
            for (int jh = 0; jh < 4; ++jh)
                cur[jh] = __builtin_nontemporal_load(
                    v4 + base4 + (size_t)(t0 + jh * 16 + rs) * 256);
        }
        for (int il = 0; il < 16; ++il) {
            const int i = ig * 16 + il;
            if (il < 15) {
#pragma unroll
                for (int jh = 0; jh < 4; ++jh)
                    nxt[jh] = __builtin_nontemporal_load(
                        v4 + base4 + (size_t)((i + 1) * 64 + jh * 16 + rs) * 256);
            }
            v4f p = (v4f)0.f;
#pragma unroll
            for (int jh = 0; jh < 4; ++jh) {
                p += cur[jh];
                vsacc[jh] += cur[jh];
            }
#pragma unroll
            for (int mask = 1; mask <= 8; mask <<= 1) {
                p.x += __shfl_xor(p.x, mask);
                p.y += __shfl_xor(p.y, mask);
                p.z += __shfl_xor(p.z, mask);
                p.w += __shfl_xor(p.w, mask);
            }
            if (rs == 0)
                *(v4f*)(us + ((size_t)bh * 64 + i) * 64 + q * 4) = p;
#pragma unroll
            for (int jh = 0; jh < 4; ++jh) cur[jh] = nxt[jh];
        }
#pragma unroll
        for (int jh = 0; jh < 4; ++jh) {
            const int j = jh * 16 + rs;
            *(v4f*)(vs_part + (((size_t)ig * 128 + bh) * 64 + j) * 64 + q * 4) =
                vsacc[jh];
        }
    } else {
        // ---- prep path: G[h][t][j] ----
        const int pb = bid - 512;
        const int h = pb >> 4, tq = pb & 15;
        __shared__ float zl[127];
        __shared__ float c127t[127], s127t[127];
        __shared__ float c126t[126], s126t[126];
        __shared__ float ZA[64], ZB[64];
        const float w127 = 6.28318530717958647692f / 127.0f;
        const float w126 = 6.28318530717958647692f / 126.0f;
        if (tid < 127) {
            zl[tid] = wgt[h * 127 + tid];
            float sv, cv; __sincosf((float)tid * w127, &sv, &cv);
            c127t[tid] = cv; s127t[tid] = sv;
        } else if (tid >= 128 && tid < 254) {
            const int m = tid - 128;
            float sv, cv; __sincosf((float)m * w126, &sv, &cv);
            c126t[m] = cv; s126t[m] = sv;
        }
        __syncthreads();
        if (tid < 64) {
            const int k = tid;
            float a = 0.f, bq = 0.f;
            int r = 0;
            for (int m = 0; m < 127; ++m) {
                a  += zl[m] * c127t[r];
                bq -= zl[m] * s127t[r];
                r += k; if (r >= 127) r -= 127;
            }
            ZA[k] = a; ZB[k] = bq;
        }
        __syncthreads();
        const int t = tq * 4 + (tid >> 6);
        const int j = tid & 63;
        const int jj = 63 + j;
        float acc = ZA[0];
        int rb = t, ra = jj;                       // k = 1 values
        for (int k = 1; k <= 62; ++k) {
            const float cA = c126t[rb], sA = s126t[rb];
            const float cB = c127t[ra], sB = s127t[ra];
            const float cAB = cA * cB + sA * sB;   // cos(A-B)
            const float sAB = sA * cB - cA * sB;   // sin(A-B)
            acc += 2.f * (ZA[k] * cAB - ZB[k] * sAB);
            rb += t;  if (rb >= 126) rb -= 126;
            ra += jj; if (ra >= 127) ra -= 127;
        }
        {   // Nyquist of length-126 inverse
            const int rn = (63 * jj) % 127;
            const float term = ZA[63] * c127t[rn] + ZB[63] * s127t[rn];
            acc += (t & 1) ? -term : term;
        }
        G[((size_t)h * 64 + t) * 64 + j] = acc * (1.0f / 126.0f);
    }
}

// ---------------------------------------------------------------------------
// Kernel 2:
//  bid < 512 : block (bh, tq). Load us/vs(+combine)/G^T into LDS; conv with
//    loop-interchange (1 b128 G^T + 1 b128 vs + 1 b128 us + 1 b32 per j);
//    store phase caches 16 rxv rows + rxu in registers, pure nt stores.
//  bid >= 512: 64 tail blocks emit out2 from G and o_.
// ---------------------------------------------------------------------------
__global__ __launch_bounds__(256) void convemit_kernel(
        const float* __restrict__ G,
        const float* __restrict__ us,
        const float* __restrict__ vs_part,
        const float* __restrict__ ovec,
        float* __restrict__ out) {
    const int bid = blockIdx.x;
    const int tid = threadIdx.x;

    __shared__ float GlT[64 * 68];     // GlT[j*68 + t] = G[t][j]
    __shared__ float usl[4096];        // [i][e]
    __shared__ float vsl[4096];        // [j][e]
    __shared__ float rxv_l[64 * 68];   // [j][e], stride 68
    __shared__ float rxu_l[16 * 68];   // [il][e]
    __shared__ float zpb[1024];        // tail: [h][n]
    __shared__ float ol[64];

    if (bid < 512) {
        const int bh = bid >> 2, tq = bid & 3;
        const int b = bh >> 4, h = bh & 15;

        for (int k = 0; k < 16; ++k) {
            const int idx = k * 256 + tid;
            usl[idx] = us[(size_t)bh * 4096 + idx];
            float a = 0.f;
#pragma unroll
            for (int ig = 0; ig < 4; ++ig)
                a += vs_part[((size_t)ig * 128 + bh) * 4096 + idx];
            vsl[idx] = a;
            GlT[(idx & 63) * 68 + (idx >> 6)] = G[(size_t)h * 4096 + idx];
        }
        __syncthreads();

        const int tb = tid >> 4;           // 0..15: rxv rows 4tb..4tb+3, rxu row tq*16+tb
        const int q  = tid & 15;           // e-chunk (float4)
        const int i_row = tq * 16 + tb;
        const v4f* us4 = (const v4f*)usl;
        const v4f* vs4 = (const v4f*)vsl;

        v4f accV[4];
#pragma unroll
        for (int r = 0; r < 4; ++r) accV[r] = (v4f)0.f;
        v4f accU = (v4f)0.f;
#pragma unroll 8
        for (int j = 0; j < 64; ++j) {
            const v4f gv = *(const v4f*)&GlT[j * 68 + tb * 4];
            const float gu = GlT[j * 68 + i_row];
            const v4f vv = vs4[j * 16 + q];
            const v4f uu = us4[j * 16 + q];
            accV[0] += gv.x * vv;
            accV[1] += gv.y * vv;
            accV[2] += gv.z * vv;
            accV[3] += gv.w * vv;
            accU += gu * uu;
        }
#pragma unroll
        for (int r = 0; r < 4; ++r)
            *(v4f*)&rxv_l[(tb * 4 + r) * 68 + q * 4] = accV[r];
        *(v4f*)&rxu_l[tb * 68 + q * 4] = accU;
        __syncthreads();

        // store phase: wave w covers j == w (mod 4); cache its 16 rxv rows.
        const int w = tid >> 6, lane = tid & 63;
        float rv[16];
#pragma unroll
        for (int jj = 0; jj < 16; ++jj)
            rv[jj] = rxv_l[(jj * 4 + w) * 68 + lane];
        const size_t obase = (((size_t)b * 4096 + tq * 1024) * 16 + h) * 64 + lane;
        for (int il = 0; il < 16; ++il) {
            const float ru = rxu_l[il * 68 + lane];
#pragma unroll
            for (int jj = 0; jj < 16; ++jj) {
                const int j = jj * 4 + w;
                __builtin_nontemporal_store(rv[jj] + ru,
                    out + obase + (size_t)(il * 64 + j) * 1024);
            }
        }
    } else {
        const int bz = bid - 512;          // 0..63: the t>>6 coordinate
        if (tid < 64) ol[tid] = ovec[tid];
        __syncthreads();
#pragma unroll
        for (int r = 0; r < 4; ++r) {
            const int idx = tid + 256 * r;
            const int h = idx >> 6, n = idx & 63;
            float acc = 0.f;
            for (int j = 0; j < 64; ++j)
                acc += ol[j] * G[(size_t)h * 4096 + n * 64 + j];
            zpb[idx] = acc * 64.f;         // * s
        }
        __syncthreads();
#pragma unroll
        for (int r = 0; r < 4; ++r) {
            const int k = tid + 256 * r;
            const int hh = k & 15, c = k >> 4;
            out[OUT2_OFF + ((size_t)(bz * 64 + c)) * 16 + hh] =
                zpb[hh * 64 + c] + zpb[hh * 64 + bz];
        }
    }
}

extern "C" void kernel_launch(void* const* d_in, const int* in_sizes, int n_in,
                              void* d_out, int out_size, void* d_ws, size_t ws_size,
                              hipStream_t stream) {
    const float* v    = (const float*)d_in[0];   // (8,4096,16,64) f32
    const float* wgt  = (const float*)d_in[1];   // (1,16,127) f32
    const float* ovec = (const float*)d_in[2];   // (64,) f32

    float* G       = (float*)d_ws;               // 65536 floats
    float* us      = G + 65536;                  // 524288 floats
    float* vs_part = us + 524288;                // 2097152 floats
    float* out     = (float*)d_out;

    hipLaunchKernelGGL(fused1_kernel,   dim3(512 + 256), dim3(256), 0, stream,
                       v, wgt, us, vs_part, G);
    hipLaunchKernelGGL(convemit_kernel, dim3(512 + 64),  dim3(256), 0, stream,
                       G, us, vs_part, ovec, out);
}